// Round 1
// baseline (179.505 us; speedup 1.0000x reference)
//
#include <hip/hip_runtime.h>
#include <math.h>

#define N_NODES 16384
#define CIN 128
#define HOUT 256          // HEADS * OUT_CH
#define OUTC 128
#define SPATIAL 8192      // D*H*W
#define NEG_ATT 0.2f
#define NEG_ACT 0.01f
#define BN_EPS 1e-5f

// ---------------- GEMM: h[n][o] = sum_k x[b][k][s] * lin_w[k][o] + lin_b[o] ----------------
// n = b*8192 + s.  Tile 64 nodes x 64 outs, K chunks of 32. block=256, thread computes 4x4.
__global__ __launch_bounds__(256) void gemm_kernel(const float* __restrict__ x,
                                                   const float* __restrict__ lin_w,
                                                   const float* __restrict__ lin_b,
                                                   float* __restrict__ h) {
    __shared__ float As[32][64];   // [k][node]
    __shared__ float Bs[32][64];   // [k][out]
    const int t = threadIdx.x;
    const int n0 = blockIdx.y * 64;
    const int o0 = blockIdx.x * 64;
    const int b = n0 >> 13;          // /8192 (tiles never straddle batches: 8192%64==0)
    const int s0 = n0 & 8191;
    const int tx = t & 15;           // out group (4 outs)
    const int ty = t >> 4;           // node group (4 nodes)
    float acc[4][4] = {};

    const int col = t & 63;
    const int r0 = t >> 6;           // 0..3

    for (int kk = 0; kk < CIN; kk += 32) {
#pragma unroll
        for (int kr = 0; kr < 32; kr += 4) {
            int k = kk + kr + r0;
            As[kr + r0][col] = x[((b * CIN + k) << 13) + s0 + col];
            Bs[kr + r0][col] = lin_w[k * HOUT + o0 + col];
        }
        __syncthreads();
#pragma unroll
        for (int k = 0; k < 32; k++) {
            float4 av = ((const float4*)(&As[k][0]))[ty];
            float4 bv = ((const float4*)(&Bs[k][0]))[tx];
            float a[4] = {av.x, av.y, av.z, av.w};
            float bb[4] = {bv.x, bv.y, bv.z, bv.w};
#pragma unroll
            for (int i = 0; i < 4; i++)
#pragma unroll
                for (int j = 0; j < 4; j++)
                    acc[i][j] = fmaf(a[i], bb[j], acc[i][j]);
        }
        __syncthreads();
    }
    float4 lb = *(const float4*)(&lin_b[o0 + tx * 4]);
#pragma unroll
    for (int i = 0; i < 4; i++) {
        int n = n0 + ty * 4 + i;
        float4 o;
        o.x = acc[i][0] + lb.x;
        o.y = acc[i][1] + lb.y;
        o.z = acc[i][2] + lb.z;
        o.w = acc[i][3] + lb.w;
        *(float4*)(&h[n * HOUT + o0 + tx * 4]) = o;
    }
}

// ---------------- CSR build ----------------
__global__ void count_kernel(const int* __restrict__ dst, int* __restrict__ deg, int E) {
    int e = blockIdx.x * 256 + threadIdx.x;
    if (e < E) atomicAdd(&deg[dst[e]], 1);
}

// one block, 1024 threads, 16 nodes each (16384 total)
__global__ __launch_bounds__(1024) void scan_kernel(const int* __restrict__ deg,
                                                    int* __restrict__ row_ptr,
                                                    int* __restrict__ cursor) {
    __shared__ int sums[1024];
    const int t = threadIdx.x;
    int local[16];
    int s = 0;
#pragma unroll
    for (int k = 0; k < 16; k++) {
        local[k] = deg[t * 16 + k];
        s += local[k];
    }
    sums[t] = s;
    __syncthreads();
    for (int off = 1; off < 1024; off <<= 1) {
        int v = (t >= off) ? sums[t - off] : 0;
        __syncthreads();
        sums[t] += v;
        __syncthreads();
    }
    int run = sums[t] - s;   // exclusive
#pragma unroll
    for (int k = 0; k < 16; k++) {
        row_ptr[t * 16 + k] = run;
        cursor[t * 16 + k] = run;
        run += local[k];
    }
    if (t == 1023) row_ptr[N_NODES] = run;
}

__global__ void scatter_kernel(const int* __restrict__ edges, int* __restrict__ cursor,
                               int* __restrict__ csr, int E) {
    int e = blockIdx.x * 256 + threadIdx.x;
    if (e < E) {
        int s = edges[e];
        int d = edges[E + e];
        int p = atomicAdd(&cursor[d], 1);
        csr[p] = s;
    }
}

// ---------------- GAT: one wave per node, online softmax over incoming edges ----------------
__global__ __launch_bounds__(256) void gat_kernel(const float* __restrict__ h,
                                                  const int* __restrict__ row_ptr,
                                                  const int* __restrict__ csr,
                                                  const float* __restrict__ att,
                                                  const float* __restrict__ gat_bias,
                                                  float* __restrict__ gat) {
    const int t = threadIdx.x;
    const int lane = t & 63;
    const int node = (blockIdx.x << 2) + (t >> 6);
    const float4* __restrict__ h4 = (const float4*)h;

    float4 hd = h4[(node << 6) + lane];          // h[node][4*lane .. 4*lane+3]
    float4 a4 = ((const float4*)att)[lane];      // att flat [head*128 + c] == [4*lane..]
    float m = -INFINITY, denom = 0.0f;
    float4 acc = make_float4(0.f, 0.f, 0.f, 0.f);

    const int beg = row_ptr[node];
    const int end = row_ptr[node + 1];
    const int cnt = end - beg + 1;               // + self loop

    int j = node;                                // self loop first
    for (int e = 0; e < cnt; e++) {
        float4 hj = h4[(j << 6) + lane];
        // prefetch next src index (wave-uniform scalar load)
        if (e + 1 < cnt) j = csr[beg + e];
        float vx = hj.x + hd.x; vx = vx > 0.f ? vx : NEG_ATT * vx;
        float vy = hj.y + hd.y; vy = vy > 0.f ? vy : NEG_ATT * vy;
        float vz = hj.z + hd.z; vz = vz > 0.f ? vz : NEG_ATT * vz;
        float vw = hj.w + hd.w; vw = vw > 0.f ? vw : NEG_ATT * vw;
        float p = vx * a4.x + vy * a4.y + vz * a4.z + vw * a4.w;
        // reduce within each 32-lane half (per head)
        p += __shfl_xor(p, 1);
        p += __shfl_xor(p, 2);
        p += __shfl_xor(p, 4);
        p += __shfl_xor(p, 8);
        p += __shfl_xor(p, 16);
        float nm = fmaxf(m, p);
        float scale = __expf(m - nm);
        float w = __expf(p - nm);
        denom = denom * scale + w;
        acc.x = acc.x * scale + w * hj.x;
        acc.y = acc.y * scale + w * hj.y;
        acc.z = acc.z * scale + w * hj.z;
        acc.w = acc.w * scale + w * hj.w;
        m = nm;
    }
    float inv = 1.0f / denom;
    float rx = acc.x * inv, ry = acc.y * inv, rz = acc.z * inv, rw = acc.w * inv;
    // combine heads: lane l (<32) pairs with lane l+32 holding head1's same channels
    rx += __shfl_xor(rx, 32);
    ry += __shfl_xor(ry, 32);
    rz += __shfl_xor(rz, 32);
    rw += __shfl_xor(rw, 32);
    if (lane < 32) {
        float4 gb = ((const float4*)gat_bias)[lane];
        float4 o;
        o.x = 0.5f * rx + gb.x;
        o.y = 0.5f * ry + gb.y;
        o.z = 0.5f * rz + gb.z;
        o.w = 0.5f * rw + gb.w;
        ((float4*)gat)[(node << 5) + lane] = o;
    }
}

// ---------------- BN stats ----------------
__global__ __launch_bounds__(256) void bn_reduce(const float* __restrict__ gat,
                                                 float* __restrict__ gsum,
                                                 float* __restrict__ gsumsq, int total) {
    __shared__ float ssum[256], ssq[256];
    const int t = threadIdx.x;
    float s = 0.f, q = 0.f;
    for (int i = blockIdx.x * 256 + t; i < total; i += 256 * gridDim.x) {
        float v = gat[i];
        s += v;
        q += v * v;
    }
    ssum[t] = s;
    ssq[t] = q;
    __syncthreads();
    if (t < 128) {
        atomicAdd(&gsum[t], ssum[t] + ssum[t + 128]);
        atomicAdd(&gsumsq[t], ssq[t] + ssq[t + 128]);
    }
}

__global__ void bn_final(const float* __restrict__ gsum, const float* __restrict__ gsumsq,
                         const float* __restrict__ gamma, const float* __restrict__ beta,
                         float* __restrict__ scsh) {
    int c = threadIdx.x;
    const float invN = 1.0f / (float)N_NODES;
    float mean = gsum[c] * invN;
    float var = gsumsq[c] * invN - mean * mean;
    float rstd = rsqrtf(var + BN_EPS);
    float sc = gamma[c] * rstd;
    scsh[c] = sc;
    scsh[128 + c] = beta[c] - mean * sc;
}

// ---------------- epilogue: affine + lrelu + transpose to (B,C,D,H,W) ----------------
__global__ __launch_bounds__(256) void epilogue_kernel(const float* __restrict__ gat,
                                                       const float* __restrict__ scsh,
                                                       float* __restrict__ out) {
    __shared__ float tile[64 * 129];
    __shared__ float sc[128], sh[128];
    const int t = threadIdx.x;
    if (t < 128) sc[t] = scsh[t];
    else sh[t - 128] = scsh[t];
    __syncthreads();
    const int n0 = blockIdx.x * 64;
    const int b = n0 >> 13;
    const int s0 = n0 & 8191;
#pragma unroll
    for (int k = 0; k < 32; k++) {
        int f = t + k * 256;
        int nl = f >> 7;
        int c = f & 127;
        float v = gat[(n0 << 7) + f];
        v = v * sc[c] + sh[c];
        v = v > 0.f ? v : NEG_ACT * v;
        tile[nl * 129 + c] = v;
    }
    __syncthreads();
    const int sl = t & 63;
    const int c0 = t >> 6;
#pragma unroll
    for (int k = 0; k < 32; k++) {
        int c = c0 + (k << 2);
        out[((b * OUTC + c) << 13) + s0 + sl] = tile[sl * 129 + c];
    }
}

extern "C" void kernel_launch(void* const* d_in, const int* in_sizes, int n_in,
                              void* d_out, int out_size, void* d_ws, size_t ws_size,
                              hipStream_t stream) {
    const float* x        = (const float*)d_in[0];
    const int*   edges    = (const int*)d_in[1];
    const float* lin_w    = (const float*)d_in[2];
    const float* lin_b    = (const float*)d_in[3];
    const float* att      = (const float*)d_in[4];
    const float* gat_bias = (const float*)d_in[5];
    const float* bn_gamma = (const float*)d_in[6];
    const float* bn_beta  = (const float*)d_in[7];
    float* out = (float*)d_out;
    const int E = in_sizes[1] / 2;

    char* ws = (char*)d_ws;
    float* h       = (float*)(ws);                       // 16384*256*4 = 16 MB
    float* gat     = (float*)(ws + 16777216);            // 16384*128*4 = 8 MB
    int*   deg     = (int*)(ws + 25165824);              // 64 KB
    int*   row_ptr = (int*)(ws + 25231360);              // 16385 ints
    int*   cursor  = (int*)(ws + 25297152);              // 64 KB
    int*   csr     = (int*)(ws + 25362688);              // E ints (768 KB)
    float* gsum    = (float*)(ws + 26214400);            // 128
    float* gsumsq  = gsum + 128;                         // 128
    float* scsh    = gsum + 256;                         // 256

    hipMemsetAsync(deg, 0, N_NODES * sizeof(int), stream);
    hipMemsetAsync(gsum, 0, 256 * sizeof(float), stream);

    gemm_kernel<<<dim3(HOUT / 64, N_NODES / 64), 256, 0, stream>>>(x, lin_w, lin_b, h);
    count_kernel<<<(E + 255) / 256, 256, 0, stream>>>(edges + E, deg, E);
    scan_kernel<<<1, 1024, 0, stream>>>(deg, row_ptr, cursor);
    scatter_kernel<<<(E + 255) / 256, 256, 0, stream>>>(edges, cursor, csr, E);
    gat_kernel<<<N_NODES / 4, 256, 0, stream>>>(h, row_ptr, csr, att, gat_bias, gat);
    bn_reduce<<<256, 256, 0, stream>>>(gat, gsum, gsumsq, N_NODES * OUTC);
    bn_final<<<1, 128, 0, stream>>>(gsum, gsumsq, bn_gamma, bn_beta, scsh);
    epilogue_kernel<<<N_NODES / 64, 256, 0, stream>>>(gat, scsh, out);
}

// Round 2
// 167.506 us; speedup vs baseline: 1.0716x; 1.0716x over previous
//
#include <hip/hip_runtime.h>
#include <math.h>

#define N_NODES 16384
#define CIN 128
#define HOUT 256          // HEADS * OUT_CH
#define OUTC 128
#define NEG_ATT 0.2f
#define NEG_ACT 0.01f
#define BN_EPS 1e-5f

static __device__ __forceinline__ unsigned short f2bf(float f) {
    unsigned int u = __float_as_uint(f);
    unsigned int r = (u + 0x7FFFu + ((u >> 16) & 1u)) >> 16;   // round-nearest-even
    return (unsigned short)r;
}
static __device__ __forceinline__ float bf2f(unsigned short s) {
    return __uint_as_float(((unsigned int)s) << 16);
}

// ---------------- GEMM: h[n][o] = sum_k x[b][k][s] * lin_w[k][o] + lin_b[o], bf16 output ----
__global__ __launch_bounds__(256) void gemm_kernel(const float* __restrict__ x,
                                                   const float* __restrict__ lin_w,
                                                   const float* __restrict__ lin_b,
                                                   unsigned short* __restrict__ h) {
    __shared__ float As[32][64];   // [k][node]
    __shared__ float Bs[32][64];   // [k][out]
    const int t = threadIdx.x;
    const int n0 = blockIdx.y * 64;
    const int o0 = blockIdx.x * 64;
    const int b = n0 >> 13;          // /8192 (tiles never straddle batches: 8192%64==0)
    const int s0 = n0 & 8191;
    const int tx = t & 15;           // out group (4 outs)
    const int ty = t >> 4;           // node group (4 nodes)
    float acc[4][4] = {};

    const int col = t & 63;
    const int r0 = t >> 6;           // 0..3

    for (int kk = 0; kk < CIN; kk += 32) {
#pragma unroll
        for (int kr = 0; kr < 32; kr += 4) {
            int k = kk + kr + r0;
            As[kr + r0][col] = x[((b * CIN + k) << 13) + s0 + col];
            Bs[kr + r0][col] = lin_w[k * HOUT + o0 + col];
        }
        __syncthreads();
#pragma unroll
        for (int k = 0; k < 32; k++) {
            float4 av = ((const float4*)(&As[k][0]))[ty];
            float4 bv = ((const float4*)(&Bs[k][0]))[tx];
            float a[4] = {av.x, av.y, av.z, av.w};
            float bb[4] = {bv.x, bv.y, bv.z, bv.w};
#pragma unroll
            for (int i = 0; i < 4; i++)
#pragma unroll
                for (int j = 0; j < 4; j++)
                    acc[i][j] = fmaf(a[i], bb[j], acc[i][j]);
        }
        __syncthreads();
    }
    float4 lb = *(const float4*)(&lin_b[o0 + tx * 4]);
#pragma unroll
    for (int i = 0; i < 4; i++) {
        int n = n0 + ty * 4 + i;
        ushort4 o;
        o.x = f2bf(acc[i][0] + lb.x);
        o.y = f2bf(acc[i][1] + lb.y);
        o.z = f2bf(acc[i][2] + lb.z);
        o.w = f2bf(acc[i][3] + lb.w);
        ((ushort4*)h)[n * 64 + (o0 >> 2) + tx] = o;
    }
}

// ---------------- CSR build ----------------
__global__ void count_kernel(const int* __restrict__ dst, int* __restrict__ deg, int E) {
    int e = blockIdx.x * 256 + threadIdx.x;
    if (e < E) atomicAdd(&deg[dst[e]], 1);
}

// one block, 1024 threads, 16 nodes each (16384 total)
__global__ __launch_bounds__(1024) void scan_kernel(const int* __restrict__ deg,
                                                    int* __restrict__ row_ptr,
                                                    int* __restrict__ cursor) {
    __shared__ int sums[1024];
    const int t = threadIdx.x;
    int local[16];
    int s = 0;
#pragma unroll
    for (int k = 0; k < 16; k++) {
        local[k] = deg[t * 16 + k];
        s += local[k];
    }
    sums[t] = s;
    __syncthreads();
    for (int off = 1; off < 1024; off <<= 1) {
        int v = (t >= off) ? sums[t - off] : 0;
        __syncthreads();
        sums[t] += v;
        __syncthreads();
    }
    int run = sums[t] - s;   // exclusive
#pragma unroll
    for (int k = 0; k < 16; k++) {
        row_ptr[t * 16 + k] = run;
        cursor[t * 16 + k] = run;
        run += local[k];
    }
    if (t == 1023) row_ptr[N_NODES] = run;
}

__global__ void scatter_kernel(const int* __restrict__ edges, int* __restrict__ cursor,
                               int* __restrict__ csr, int E) {
    int e = blockIdx.x * 256 + threadIdx.x;
    if (e < E) {
        int s = edges[e];
        int d = edges[E + e];
        int p = atomicAdd(&cursor[d], 1);
        csr[p] = s;
    }
}

// ---------------- GAT: one wave per node, online softmax, 4-wide edge unroll ----------------
__global__ __launch_bounds__(256) void gat_kernel(const unsigned short* __restrict__ h,
                                                  const int* __restrict__ row_ptr,
                                                  const int* __restrict__ csr,
                                                  const float* __restrict__ att,
                                                  const float* __restrict__ gat_bias,
                                                  float* __restrict__ gat) {
    const int t = threadIdx.x;
    const int lane = t & 63;
    const int node = (blockIdx.x << 2) + (t >> 6);
    const ushort4* __restrict__ h4 = (const ushort4*)h;

    ushort4 hd4 = h4[(node << 6) + lane];        // h[node][4*lane .. 4*lane+3]
    float hdx = bf2f(hd4.x), hdy = bf2f(hd4.y), hdz = bf2f(hd4.z), hdw = bf2f(hd4.w);
    float4 a4 = ((const float4*)att)[lane];      // att flat [head*128 + c] == [4*lane..]
    float m = -INFINITY, denom = 0.0f;
    float4 acc = make_float4(0.f, 0.f, 0.f, 0.f);

    const int beg = row_ptr[node];
    const int end = row_ptr[node + 1];
    const int cnt = end - beg + 1;               // + self loop (e==0)

    for (int base = 0; base < cnt; base += 4) {
        int j[4];
#pragma unroll
        for (int u = 0; u < 4; u++) {
            int e = base + u;
            j[u] = (e == 0 || e >= cnt) ? node : csr[beg + e - 1];
        }
        float4 hj[4];
        float p[4];
#pragma unroll
        for (int u = 0; u < 4; u++) {
            ushort4 hv = h4[(j[u] << 6) + lane];
            hj[u].x = bf2f(hv.x); hj[u].y = bf2f(hv.y);
            hj[u].z = bf2f(hv.z); hj[u].w = bf2f(hv.w);
            float vx = hj[u].x + hdx; vx = vx > 0.f ? vx : NEG_ATT * vx;
            float vy = hj[u].y + hdy; vy = vy > 0.f ? vy : NEG_ATT * vy;
            float vz = hj[u].z + hdz; vz = vz > 0.f ? vz : NEG_ATT * vz;
            float vw = hj[u].w + hdw; vw = vw > 0.f ? vw : NEG_ATT * vw;
            p[u] = vx * a4.x + vy * a4.y + vz * a4.z + vw * a4.w;
        }
        // reduce within each 32-lane half (per head); 4 independent chains interleave
#pragma unroll
        for (int s = 1; s <= 16; s <<= 1) {
#pragma unroll
            for (int u = 0; u < 4; u++) p[u] += __shfl_xor(p[u], s);
        }
#pragma unroll
        for (int u = 0; u < 4; u++)
            if (base + u >= cnt) p[u] = -INFINITY;
        float nm = m;
#pragma unroll
        for (int u = 0; u < 4; u++) nm = fmaxf(nm, p[u]);
        float scale = __expf(m - nm);
        float w[4];
#pragma unroll
        for (int u = 0; u < 4; u++) w[u] = __expf(p[u] - nm);
        denom = denom * scale + w[0] + w[1] + w[2] + w[3];
        acc.x = acc.x * scale + w[0] * hj[0].x + w[1] * hj[1].x + w[2] * hj[2].x + w[3] * hj[3].x;
        acc.y = acc.y * scale + w[0] * hj[0].y + w[1] * hj[1].y + w[2] * hj[2].y + w[3] * hj[3].y;
        acc.z = acc.z * scale + w[0] * hj[0].z + w[1] * hj[1].z + w[2] * hj[2].z + w[3] * hj[3].z;
        acc.w = acc.w * scale + w[0] * hj[0].w + w[1] * hj[1].w + w[2] * hj[2].w + w[3] * hj[3].w;
        m = nm;
    }
    float inv = 1.0f / denom;
    float rx = acc.x * inv, ry = acc.y * inv, rz = acc.z * inv, rw = acc.w * inv;
    // combine heads: lane l (<32) pairs with lane l+32 holding head1's same channels
    rx += __shfl_xor(rx, 32);
    ry += __shfl_xor(ry, 32);
    rz += __shfl_xor(rz, 32);
    rw += __shfl_xor(rw, 32);
    if (lane < 32) {
        float4 gb = ((const float4*)gat_bias)[lane];
        float4 o;
        o.x = 0.5f * rx + gb.x;
        o.y = 0.5f * ry + gb.y;
        o.z = 0.5f * rz + gb.z;
        o.w = 0.5f * rw + gb.w;
        ((float4*)gat)[(node << 5) + lane] = o;
    }
}

// ---------------- BN stats ----------------
__global__ __launch_bounds__(256) void bn_reduce(const float* __restrict__ gat,
                                                 float* __restrict__ gsum,
                                                 float* __restrict__ gsumsq, int total) {
    __shared__ float ssum[256], ssq[256];
    const int t = threadIdx.x;
    float s = 0.f, q = 0.f;
    for (int i = blockIdx.x * 256 + t; i < total; i += 256 * gridDim.x) {
        float v = gat[i];
        s += v;
        q += v * v;
    }
    ssum[t] = s;
    ssq[t] = q;
    __syncthreads();
    if (t < 128) {
        atomicAdd(&gsum[t], ssum[t] + ssum[t + 128]);
        atomicAdd(&gsumsq[t], ssq[t] + ssq[t + 128]);
    }
}

// ---------------- epilogue: BN finalize + affine + lrelu + transpose to (B,C,D,H,W) --------
__global__ __launch_bounds__(256) void epilogue_kernel(const float* __restrict__ gat,
                                                       const float* __restrict__ gsum,
                                                       const float* __restrict__ gsumsq,
                                                       const float* __restrict__ gamma,
                                                       const float* __restrict__ beta,
                                                       float* __restrict__ out) {
    __shared__ float tile[64 * 129];
    __shared__ float sc[128], sh[128];
    const int t = threadIdx.x;
    if (t < 128) {
        const float invN = 1.0f / (float)N_NODES;
        float mean = gsum[t] * invN;
        float var = gsumsq[t] * invN - mean * mean;
        float rstd = rsqrtf(var + BN_EPS);
        float s = gamma[t] * rstd;
        sc[t] = s;
        sh[t] = beta[t] - mean * s;
    }
    __syncthreads();
    const int n0 = blockIdx.x * 64;
    const int b = n0 >> 13;
    const int s0 = n0 & 8191;
#pragma unroll
    for (int k = 0; k < 32; k++) {
        int f = t + k * 256;
        int nl = f >> 7;
        int c = f & 127;
        float v = gat[(n0 << 7) + f];
        v = v * sc[c] + sh[c];
        v = v > 0.f ? v : NEG_ACT * v;
        tile[nl * 129 + c] = v;
    }
    __syncthreads();
    const int sl = t & 63;
    const int c0 = t >> 6;
#pragma unroll
    for (int k = 0; k < 32; k++) {
        int c = c0 + (k << 2);
        out[((b * OUTC + c) << 13) + s0 + sl] = tile[sl * 129 + c];
    }
}

extern "C" void kernel_launch(void* const* d_in, const int* in_sizes, int n_in,
                              void* d_out, int out_size, void* d_ws, size_t ws_size,
                              hipStream_t stream) {
    const float* x        = (const float*)d_in[0];
    const int*   edges    = (const int*)d_in[1];
    const float* lin_w    = (const float*)d_in[2];
    const float* lin_b    = (const float*)d_in[3];
    const float* att      = (const float*)d_in[4];
    const float* gat_bias = (const float*)d_in[5];
    const float* bn_gamma = (const float*)d_in[6];
    const float* bn_beta  = (const float*)d_in[7];
    float* out = (float*)d_out;
    const int E = in_sizes[1] / 2;

    char* ws = (char*)d_ws;
    unsigned short* h = (unsigned short*)(ws);           // 16384*256*2 = 8 MB
    float* gat     = (float*)(ws + 8388608);             // 16384*128*4 = 8 MB
    int*   deg     = (int*)(ws + 16777216);              // 64 KB
    int*   row_ptr = (int*)(ws + 16842752);              // 16385 ints
    int*   cursor  = (int*)(ws + 16912384);              // 64 KB
    int*   csr     = (int*)(ws + 16977920);              // E ints (768 KB)
    float* gsum    = (float*)(ws + 17764352);            // 128
    float* gsumsq  = gsum + 128;                         // 128

    hipMemsetAsync(deg, 0, N_NODES * sizeof(int), stream);
    hipMemsetAsync(gsum, 0, 256 * sizeof(float), stream);

    gemm_kernel<<<dim3(HOUT / 64, N_NODES / 64), 256, 0, stream>>>(x, lin_w, lin_b, h);
    count_kernel<<<(E + 255) / 256, 256, 0, stream>>>(edges + E, deg, E);
    scan_kernel<<<1, 1024, 0, stream>>>(deg, row_ptr, cursor);
    scatter_kernel<<<(E + 255) / 256, 256, 0, stream>>>(edges, cursor, csr, E);
    gat_kernel<<<N_NODES / 4, 256, 0, stream>>>(h, row_ptr, csr, att, gat_bias, gat);
    bn_reduce<<<256, 256, 0, stream>>>(gat, gsum, gsumsq, N_NODES * OUTC);
    epilogue_kernel<<<N_NODES / 64, 256, 0, stream>>>(gat, gsum, gsumsq, bn_gamma, bn_beta, out);
}